// Round 4
// baseline (4438.888 us; speedup 1.0000x reference)
//
#include <hip/hip_runtime.h>

#define NN 50000
#define EE 800000
#define TT 12
#define HH 128
#define LLAYERS 3
#define OO 12

typedef __attribute__((ext_vector_type(8))) short short8;    // 8 bf16 = 4 VGPRs
typedef __attribute__((ext_vector_type(4))) float float4v;   // MFMA acc
typedef unsigned short ushort_t;

#define MFMA_BF16 __builtin_amdgcn_mfma_f32_16x16x32_bf16

__device__ __forceinline__ ushort_t f2b(float f) {   // fp32 -> bf16 RNE
    union { float f; unsigned u; } v; v.f = f;
    unsigned u = v.u;
    return (ushort_t)((u + 0x7FFFu + ((u >> 16) & 1u)) >> 16);
}
__device__ __forceinline__ float b2f(ushort_t b) {
    union { unsigned u; float f; } v; v.u = ((unsigned)b) << 16; return v.f;
}
__device__ __forceinline__ short8 ld8(const ushort_t* p) { return *(const short8*)p; }

__device__ __forceinline__ float sigf(float x) { return 1.f / (1.f + __expf(-x)); }
__device__ __forceinline__ float tanhfast(float x) {
    float a = fabsf(x);
    float t = __expf(-2.f * a);
    float r = (1.f - t) / (1.f + t);
    return copysignf(r, x);
}

// LDS tile helpers: [16][128] bf16 tile (256 B rows), XOR-swizzled (G4).
__device__ __forceinline__ short8 lds_frag(const ushort_t* tile, int row, int kb) {
    int off = (row << 8) + kb;
    off ^= (row & 7) << 4;
    return *(const short8*)((const char*)tile + off);
}
__device__ __forceinline__ void lds_wr16(ushort_t* tile, int row, int cb, ushort_t v) {
    int off = (row << 8) + cb;
    off ^= (row & 7) << 4;
    *(ushort_t*)((char*)tile + off) = v;
}

// ---------------------------------------------------------------------------
// Persistent 2-layer GRU over all 12 timesteps. h0/h1 live in LDS (bf16,
// swizzled) + fp32 register masters. No global h traffic inside the loop.
// Wave owns 16 rows; block = 4 waves = 64 rows. No cross-wave data sharing;
// per-t __syncthreads only aligns waves on the weight stream for L1 reuse.
// ---------------------------------------------------------------------------
__global__ __launch_bounds__(256, 2)
void gru_all(const float* __restrict__ x,
             const ushort_t* __restrict__ Whh0b, const float* __restrict__ Wih0,
             const float* __restrict__ bih0, const float* __restrict__ bhh0,
             const ushort_t* __restrict__ Wih1b, const ushort_t* __restrict__ Whh1b,
             const float* __restrict__ bih1, const float* __restrict__ bhh1,
             float* __restrict__ h1f, ushort_t* __restrict__ h1b) {
    __shared__ ushort_t h0s[4][2048];   // 4 waves x [16][128] bf16
    __shared__ ushort_t h1s[4][2048];
    __shared__ float xs[4][192];        // 4 waves x [16 rows][12 t]
    __shared__ float prm[1920];         // Wih0|bih0|bhh0|bih1|bhh1 (384 each)

    const int tid = threadIdx.x;
    const int wave = tid >> 6, lane = tid & 63;
    const int col = lane & 15, kg = lane >> 4;
    const int r0 = (blockIdx.x * 4 + wave) * 16;

    // stage params
    for (int q = tid; q < 1920; q += 256) {
        const float* s;
        int o = q;
        if (q < 384)       { s = Wih0; }
        else if (q < 768)  { s = bih0; o -= 384; }
        else if (q < 1152) { s = bhh0; o -= 768; }
        else if (q < 1536) { s = bih1; o -= 1152; }
        else               { s = bhh1; o -= 1536; }
        prm[q] = s[o];
    }
    // stage x rows for this wave
    for (int q = lane; q < 192; q += 64) {
        int row = q / 12, tc = q % 12;
        int node = r0 + row;
        xs[wave][q] = (node < NN) ? x[(size_t)node * TT + tc] : 0.f;
    }
    // zero h tiles (wave-local)
    for (int q = lane; q < 256; q += 64) {
        ((int4*)h0s[wave])[q] = make_int4(0, 0, 0, 0);
        ((int4*)h1s[wave])[q] = make_int4(0, 0, 0, 0);
    }
    float h0r[32] = {};
    float h1r[32] = {};

#pragma unroll 1
    for (int t = 0; t < TT; ++t) {
        __syncthreads();
        // ---------------- layer 0 ----------------
        short8 a[4];
#pragma unroll
        for (int ks = 0; ks < 4; ++ks)
            a[ks] = lds_frag(h0s[wave], col, ks * 64 + kg * 16);
        float xv[4];
#pragma unroll
        for (int i = 0; i < 4; ++i)
            xv[i] = xs[wave][(kg * 4 + i) * 12 + t];
#pragma unroll
        for (int j0 = 0; j0 < 8; ++j0) {
            float4v aR = {0,0,0,0}, aZ = {0,0,0,0}, aN = {0,0,0,0};
            const ushort_t* bp = Whh0b + (size_t)(j0 * 16 + col) * HH + kg * 8;
#pragma unroll
            for (int ks = 0; ks < 4; ++ks) {
                aR = MFMA_BF16(a[ks], ld8(bp + ks * 32), aR, 0, 0, 0);
                aZ = MFMA_BF16(a[ks], ld8(bp + 128 * HH + ks * 32), aZ, 0, 0, 0);
                aN = MFMA_BF16(a[ks], ld8(bp + 256 * HH + ks * 32), aN, 0, 0, 0);
            }
            const int jj = j0 * 16 + col;
            const float wR = prm[jj], wZ = prm[jj + 128], wN = prm[jj + 256];
            const float biR = prm[384 + jj], biZ = prm[384 + jj + 128], biN = prm[384 + jj + 256];
            const float bhR = prm[768 + jj], bhZ = prm[768 + jj + 128], bhN = prm[768 + jj + 256];
#pragma unroll
            for (int i = 0; i < 4; ++i) {
                float hold = h0r[j0 * 4 + i];
                float r = sigf(xv[i] * wR + biR + aR[i] + bhR);
                float z = sigf(xv[i] * wZ + biZ + aZ[i] + bhZ);
                float nn2 = tanhfast(xv[i] * wN + biN + r * (aN[i] + bhN));
                float hn = (1.f - z) * nn2 + z * hold;
                h0r[j0 * 4 + i] = hn;
                lds_wr16(h0s[wave], kg * 4 + i, jj * 2, f2b(hn));
            }
        }
        // ---------------- layer 1 ----------------
        short8 an[4], a1[4];
#pragma unroll
        for (int ks = 0; ks < 4; ++ks) {
            an[ks] = lds_frag(h0s[wave], col, ks * 64 + kg * 16);
            a1[ks] = lds_frag(h1s[wave], col, ks * 64 + kg * 16);
        }
#pragma unroll
        for (int j0 = 0; j0 < 8; ++j0) {
            float4v xR = {0,0,0,0}, xZ = {0,0,0,0}, xN = {0,0,0,0};
            float4v hR = {0,0,0,0}, hZ = {0,0,0,0}, hN = {0,0,0,0};
            const ushort_t* bpx = Wih1b + (size_t)(j0 * 16 + col) * HH + kg * 8;
            const ushort_t* bph = Whh1b + (size_t)(j0 * 16 + col) * HH + kg * 8;
#pragma unroll
            for (int ks = 0; ks < 4; ++ks) {
                xR = MFMA_BF16(an[ks], ld8(bpx + ks * 32), xR, 0, 0, 0);
                xZ = MFMA_BF16(an[ks], ld8(bpx + 128 * HH + ks * 32), xZ, 0, 0, 0);
                xN = MFMA_BF16(an[ks], ld8(bpx + 256 * HH + ks * 32), xN, 0, 0, 0);
                hR = MFMA_BF16(a1[ks], ld8(bph + ks * 32), hR, 0, 0, 0);
                hZ = MFMA_BF16(a1[ks], ld8(bph + 128 * HH + ks * 32), hZ, 0, 0, 0);
                hN = MFMA_BF16(a1[ks], ld8(bph + 256 * HH + ks * 32), hN, 0, 0, 0);
            }
            const int jj = j0 * 16 + col;
            const float biR = prm[1152 + jj], biZ = prm[1152 + jj + 128], biN = prm[1152 + jj + 256];
            const float bhR = prm[1536 + jj], bhZ = prm[1536 + jj + 128], bhN = prm[1536 + jj + 256];
#pragma unroll
            for (int i = 0; i < 4; ++i) {
                float hold = h1r[j0 * 4 + i];
                float r = sigf(xR[i] + biR + hR[i] + bhR);
                float z = sigf(xZ[i] + biZ + hZ[i] + bhZ);
                float nn2 = tanhfast(xN[i] + biN + r * (hN[i] + bhN));
                float hn = (1.f - z) * nn2 + z * hold;
                h1r[j0 * 4 + i] = hn;
                lds_wr16(h1s[wave], kg * 4 + i, jj * 2, f2b(hn));
            }
        }
    }
    // write h1 out (fp32 master + bf16)
#pragma unroll
    for (int j0 = 0; j0 < 8; ++j0) {
        const int jj = j0 * 16 + col;
#pragma unroll
        for (int i = 0; i < 4; ++i) {
            int node = r0 + kg * 4 + i;
            if (node < NN) {
                float v = h1r[j0 * 4 + i];
                h1f[(size_t)node * HH + jj] = v;
                h1b[(size_t)node * HH + jj] = f2b(v);
            }
        }
    }
}

// ---------------------------------------------------------------------------
// Dual bf16 GEMM: xl = h1@Wl^T + bl, xr = h1@Wr^T + br (bf16 outputs only).
// ---------------------------------------------------------------------------
__global__ __launch_bounds__(256)
void gemm_dual(const ushort_t* __restrict__ A,
               const ushort_t* __restrict__ B1, const ushort_t* __restrict__ B2,
               const float* __restrict__ bias1, const float* __restrict__ bias2,
               ushort_t* __restrict__ C1, ushort_t* __restrict__ C2) {
    const int wave = threadIdx.x >> 6, lane = threadIdx.x & 63;
    const int r0 = (blockIdx.x * 4 + wave) * 16;
    const int col = lane & 15, kg = lane >> 4;
    const int arow = min(r0 + col, NN - 1);
    short8 a[4];
#pragma unroll
    for (int ks = 0; ks < 4; ++ks)
        a[ks] = ld8(A + (size_t)arow * HH + ks * 32 + kg * 8);
#pragma unroll
    for (int j0 = 0; j0 < 8; ++j0) {
        float4v c1 = {0,0,0,0}, c2 = {0,0,0,0};
        const ushort_t* p1 = B1 + (size_t)(j0 * 16 + col) * HH + kg * 8;
        const ushort_t* p2 = B2 + (size_t)(j0 * 16 + col) * HH + kg * 8;
#pragma unroll
        for (int ks = 0; ks < 4; ++ks) {
            c1 = MFMA_BF16(a[ks], ld8(p1 + ks * 32), c1, 0, 0, 0);
            c2 = MFMA_BF16(a[ks], ld8(p2 + ks * 32), c2, 0, 0, 0);
        }
        const int jj = j0 * 16 + col;
        const float b1 = bias1[jj], b2 = bias2[jj];
#pragma unroll
        for (int i = 0; i < 4; ++i) {
            int node = r0 + kg * 4 + i;
            if (node >= NN) continue;
            C1[(size_t)node * HH + jj] = f2b(c1[i] + b1);
            C2[(size_t)node * HH + jj] = f2b(c2[i] + b2);
        }
    }
}

// ---------------------------------------------------------------------------
// CSR build (by dst).
// ---------------------------------------------------------------------------
__global__ void csr_count(const int* __restrict__ dst, int* __restrict__ cursor) {
    int e = blockIdx.x * 256 + threadIdx.x;
    if (e < EE) atomicAdd(&cursor[dst[e]], 1);
}

__global__ __launch_bounds__(1024)
void csr_scan(int* __restrict__ cursor, int* __restrict__ rowptr) {
    __shared__ int wsum[16];
    __shared__ int carry_s;
    const int tid = threadIdx.x, wv = tid >> 6, ln = tid & 63;
    if (tid == 0) carry_s = 0;
    __syncthreads();
    for (int base = 0; base < NN; base += 1024) {
        int i = base + tid;
        int v = (i < NN) ? cursor[i] : 0;
        int s = v;
#pragma unroll
        for (int d = 1; d < 64; d <<= 1) {
            int t2 = __shfl_up(s, d);
            if (ln >= d) s += t2;
        }
        if (ln == 63) wsum[wv] = s;
        __syncthreads();
        if (wv == 0) {
            int ws2 = (ln < 16) ? wsum[ln] : 0;
#pragma unroll
            for (int d = 1; d < 16; d <<= 1) {
                int t2 = __shfl_up(ws2, d);
                if (ln >= d) ws2 += t2;
            }
            if (ln < 16) wsum[ln] = ws2;
        }
        __syncthreads();
        int wof = wv ? wsum[wv - 1] : 0;
        int excl = carry_s + wof + s - v;
        if (i < NN) { rowptr[i] = excl; cursor[i] = excl; }
        __syncthreads();
        if (tid == 0) carry_s += wsum[15];
    }
    if (threadIdx.x == 0) rowptr[NN] = carry_s;
}

__global__ void csr_fill(const int* __restrict__ dst, int* __restrict__ cursor,
                         int* __restrict__ eidx) {
    int e = blockIdx.x * 256 + threadIdx.x;
    if (e >= EE) return;
    int pos = atomicAdd(&cursor[dst[e]], 1);
    eidx[pos] = e;
}

// ---------------------------------------------------------------------------
// Fused GAT: per dst node (one wave), online-softmax over CSR edges, then
// bias + LayerNorm + ELU + residual. Lane owns channels 2*lane, 2*lane+1
// (same head = lane>>4) -> score reduce is 4 shfl_xor over 16 lanes.
// ---------------------------------------------------------------------------
__global__ __launch_bounds__(256)
void gat_fused(const int* __restrict__ rowptr, const int* __restrict__ eidx,
               const int* __restrict__ src, const float* __restrict__ ea,
               const ushort_t* __restrict__ xlb, const ushort_t* __restrict__ xrb,
               const float* __restrict__ We, const float* __restrict__ att,
               const float* __restrict__ gbias, const float* __restrict__ gamma,
               const float* __restrict__ beta,
               float* __restrict__ h1f, ushort_t* __restrict__ h1b) {
    const int node = (blockIdx.x * 256 + threadIdx.x) >> 6;
    const int lane = threadIdx.x & 63;
    if (node >= NN) return;
    const int c0 = lane * 2;

    unsigned rr = *(const unsigned*)(xrb + (size_t)node * HH + c0);
    const float xrA = b2f((ushort_t)(rr & 0xffffu));
    const float xrB = b2f((ushort_t)(rr >> 16));
    const float2 Wv = *(const float2*)(We + c0);
    const float2 Av = *(const float2*)(att + c0);

    const int beg = rowptr[node], end = rowptr[node + 1];
    float m = -INFINITY, accA = 0.f, accB = 0.f, den = 0.f;

    int i = beg;
    int sN = 0; float ev = 0.f; unsigned rowv = 0;
    if (i < end) {
        int eid = eidx[i]; sN = src[eid]; ev = ea[eid];
        rowv = *(const unsigned*)(xlb + (size_t)sN * HH + c0);
    }
    while (i < end) {
        int sN2 = 0; float ev2 = 0.f; unsigned rowv2 = 0;
        if (i + 1 < end) {
            int eid2 = eidx[i + 1]; sN2 = src[eid2]; ev2 = ea[eid2];
            rowv2 = *(const unsigned*)(xlb + (size_t)sN2 * HH + c0);
        }
        float xlA = b2f((ushort_t)(rowv & 0xffffu));
        float xlB = b2f((ushort_t)(rowv >> 16));
        float mA = xlA + xrA + ev * Wv.x; mA = (mA > 0.f) ? mA : 0.2f * mA;
        float mB = xlB + xrB + ev * Wv.y; mB = (mB > 0.f) ? mB : 0.2f * mB;
        float p = mA * Av.x + mB * Av.y;
        p += __shfl_xor(p, 1); p += __shfl_xor(p, 2);
        p += __shfl_xor(p, 4); p += __shfl_xor(p, 8);
        float mn = fmaxf(m, p);
        float cs = __expf(m - mn);    // 0 on first iteration (m = -inf)
        float w  = __expf(p - mn);
        accA = accA * cs + w * xlA;
        accB = accB * cs + w * xlB;
        den  = den * cs + w;
        m = mn;
        sN = sN2; ev = ev2; rowv = rowv2;
        ++i;
    }
    float invd = 1.f / fmaxf(den, 1e-16f);
    float2 gb = *(const float2*)(gbias + c0);
    float oA = accA * invd + gb.x;
    float oB = accB * invd + gb.y;

    float sum = oA + oB;
    float ssq = oA * oA + oB * oB;
#pragma unroll
    for (int off = 1; off < 64; off <<= 1) {
        sum += __shfl_xor(sum, off);
        ssq += __shfl_xor(ssq, off);
    }
    float mean = sum * (1.f / 128.f);
    float var = ssq * (1.f / 128.f) - mean * mean;
    float inv = rsqrtf(var + 1e-5f);
    float2 gm = *(const float2*)(gamma + c0);
    float2 bt = *(const float2*)(beta + c0);
    float yA = (oA - mean) * inv * gm.x + bt.x;
    float yB = (oB - mean) * inv * gm.y + bt.y;
    yA = (yA > 0.f) ? yA : expm1f(yA);
    yB = (yB > 0.f) ? yB : expm1f(yB);

    float2 hv = *(float2*)(h1f + (size_t)node * HH + c0);
    hv.x += yA; hv.y += yB;
    *(float2*)(h1f + (size_t)node * HH + c0) = hv;
    unsigned pk = (unsigned)f2b(hv.x) | ((unsigned)f2b(hv.y) << 16);
    *(unsigned*)(h1b + (size_t)node * HH + c0) = pk;
}

// ---------------------------------------------------------------------------
// Fused FC head: out = relu(h1@W1^T + b1) @ W2 + b2 via LDS round-trip.
// ---------------------------------------------------------------------------
__global__ __launch_bounds__(256)
void fc_head(const ushort_t* __restrict__ A, const ushort_t* __restrict__ W1b,
             const float* __restrict__ b1, const ushort_t* __restrict__ W2b,
             const float* __restrict__ b2, float* __restrict__ out) {
    __shared__ ushort_t hs[4][2048];
    const int wave = threadIdx.x >> 6, lane = threadIdx.x & 63;
    const int r0 = (blockIdx.x * 4 + wave) * 16;
    const int col = lane & 15, kg = lane >> 4;
    const int arow = min(r0 + col, NN - 1);
    short8 a[4];
#pragma unroll
    for (int ks = 0; ks < 4; ++ks)
        a[ks] = ld8(A + (size_t)arow * HH + ks * 32 + kg * 8);
#pragma unroll
    for (int j0 = 0; j0 < 8; ++j0) {
        float4v acc = {0,0,0,0};
        const ushort_t* bp = W1b + (size_t)(j0 * 16 + col) * HH + kg * 8;
#pragma unroll
        for (int ks = 0; ks < 4; ++ks)
            acc = MFMA_BF16(a[ks], ld8(bp + ks * 32), acc, 0, 0, 0);
        const int jj = j0 * 16 + col;
        const float bj = b1[jj];
#pragma unroll
        for (int i = 0; i < 4; ++i)
            lds_wr16(hs[wave], kg * 4 + i, jj * 2, f2b(fmaxf(acc[i] + bj, 0.f)));
    }
    // second GEMM: [16,128] @ W2b[16 padded cols][128]
    short8 f[4];
#pragma unroll
    for (int ks = 0; ks < 4; ++ks)
        f[ks] = lds_frag(hs[wave], col, ks * 64 + kg * 16);
    float4v acc2 = {0,0,0,0};
#pragma unroll
    for (int ks = 0; ks < 4; ++ks)
        acc2 = MFMA_BF16(f[ks], ld8(W2b + (size_t)col * HH + ks * 32 + kg * 8), acc2, 0, 0, 0);
    if (col < OO) {
        const float bj = b2[col];
#pragma unroll
        for (int i = 0; i < 4; ++i) {
            int node = r0 + kg * 4 + i;
            if (node < NN) out[(size_t)node * OO + col] = acc2[i] + bj;
        }
    }
}

// ---------------------------------------------------------------------------
// Weight conversion kernels
// ---------------------------------------------------------------------------
__global__ void conv_bf16(const float* __restrict__ src, ushort_t* __restrict__ dst, int n) {
    int i = blockIdx.x * 256 + threadIdx.x;
    if (i < n) dst[i] = f2b(src[i]);
}
// fp32 [128,128] -> bf16 transposed: dst[j*128+k] = src[k*128+j]
__global__ void convT_bf16(const float* __restrict__ src, ushort_t* __restrict__ dst) {
    int idx = blockIdx.x * 256 + threadIdx.x;
    if (idx >= 16384) return;
    int r = idx >> 7, c = idx & 127;
    dst[c * 128 + r] = f2b(src[r * 128 + c]);
}
// fcW2 [128,12] -> bf16 [16][128] zero-padded transposed
__global__ void conv_w2(const float* __restrict__ fcW2, ushort_t* __restrict__ W2b) {
    int idx = blockIdx.x * 256 + threadIdx.x;
    if (idx >= 2048) return;
    int j = idx >> 7, k = idx & 127;
    W2b[idx] = (j < OO) ? f2b(fcW2[k * OO + j]) : (ushort_t)0;
}

// ---------------------------------------------------------------------------
extern "C" void kernel_launch(void* const* d_in, const int* in_sizes, int n_in,
                              void* d_out, int out_size, void* d_ws, size_t ws_size,
                              hipStream_t stream) {
    const float* x     = (const float*)d_in[0];
    const int*   ei    = (const int*)d_in[1];
    const int*   src   = ei;
    const int*   dst   = ei + EE;
    const float* ea    = (const float*)d_in[2];
    const float* Wih0  = (const float*)d_in[3];
    const float* Whh0  = (const float*)d_in[4];
    const float* bih0  = (const float*)d_in[5];
    const float* bhh0  = (const float*)d_in[6];
    const float* Wih1  = (const float*)d_in[7];
    const float* Whh1  = (const float*)d_in[8];
    const float* bih1  = (const float*)d_in[9];
    const float* bhh1  = (const float*)d_in[10];
    const float* gWl   = (const float*)d_in[11];
    const float* gbl   = (const float*)d_in[12];
    const float* gWr   = (const float*)d_in[13];
    const float* gbr   = (const float*)d_in[14];
    const float* gWe   = (const float*)d_in[15];
    const float* gatt  = (const float*)d_in[16];
    const float* gbias = (const float*)d_in[17];
    const float* lng   = (const float*)d_in[18];
    const float* lnb   = (const float*)d_in[19];
    const float* fcW1  = (const float*)d_in[20];
    const float* fcb1  = (const float*)d_in[21];
    const float* fcW2  = (const float*)d_in[22];
    const float* fcb2  = (const float*)d_in[23];
    float* out = (float*)d_out;
    float* ws  = (float*)d_ws;

    const size_t NH = (size_t)NN * HH;   // 6.4M elems

    // ushort region
    ushort_t* h1b   = (ushort_t*)ws;          // NH
    ushort_t* xlb   = h1b + NH;               // NH
    ushort_t* xrb   = xlb + NH;               // NH
    ushort_t* Whh0b = xrb + NH;               // 49152
    ushort_t* Wih1b = Whh0b + 49152;
    ushort_t* Whh1b = Wih1b + 49152;
    ushort_t* WlTb  = Whh1b + 49152;          // 3*16384
    ushort_t* WrTb  = WlTb + 49152;           // 3*16384
    ushort_t* W1Tb  = WrTb + 49152;           // 16384
    ushort_t* W2Tb  = W1Tb + 16384;           // 2048
    // total ushorts = 3*NH + 5*49152 + 16384 + 2048 = 19,464,192 (even)

    float* p    = ws + (3 * NH + 5 * 49152 + 16384 + 2048) / 2;
    float* h1f  = p; p += NH;
    int* rowptr = (int*)p;
    int* cursor = rowptr + (NN + 1);
    int* eidx   = cursor + NN;

    // --- weight conversions ---
    conv_bf16<<<192, 256, 0, stream>>>(Whh0, Whh0b, 49152);
    conv_bf16<<<192, 256, 0, stream>>>(Wih1, Wih1b, 49152);
    conv_bf16<<<192, 256, 0, stream>>>(Whh1, Whh1b, 49152);
    for (int l = 0; l < LLAYERS; ++l) {
        convT_bf16<<<64, 256, 0, stream>>>(gWl + (size_t)l * 16384, WlTb + (size_t)l * 16384);
        convT_bf16<<<64, 256, 0, stream>>>(gWr + (size_t)l * 16384, WrTb + (size_t)l * 16384);
    }
    convT_bf16<<<64, 256, 0, stream>>>(fcW1, W1Tb);
    conv_w2<<<8, 256, 0, stream>>>(fcW2, W2Tb);

    // --- CSR by dst (topology shared by all 3 GAT layers) ---
    hipMemsetAsync(cursor, 0, NN * sizeof(int), stream);
    csr_count<<<(EE + 255) / 256, 256, 0, stream>>>(dst, cursor);
    csr_scan<<<1, 1024, 0, stream>>>(cursor, rowptr);
    csr_fill<<<(EE + 255) / 256, 256, 0, stream>>>(dst, cursor, eidx);

    // --- GRU: one persistent kernel for all 12 timesteps ---
    const int rowBlocks = (NN + 63) / 64;   // 782
    gru_all<<<rowBlocks, 256, 0, stream>>>(x, Whh0b, Wih0, bih0, bhh0,
                                           Wih1b, Whh1b, bih1, bhh1, h1f, h1b);

    // --- GAT layers ---
    const int fusedBlocks = (NN + 3) / 4;   // 12500
    for (int l = 0; l < LLAYERS; ++l) {
        gemm_dual<<<rowBlocks, 256, 0, stream>>>(h1b, WlTb + (size_t)l * 16384,
                                                 WrTb + (size_t)l * 16384,
                                                 gbl + l * HH, gbr + l * HH, xlb, xrb);
        gat_fused<<<fusedBlocks, 256, 0, stream>>>(rowptr, eidx, src, ea, xlb, xrb,
                                                   gWe + l * HH, gatt + l * HH,
                                                   gbias + l * HH, lng + l * HH, lnb + l * HH,
                                                   h1f, h1b);
    }

    // --- FC head (fused FC1+FC2) ---
    fc_head<<<rowBlocks, 256, 0, stream>>>(h1b, W1Tb, fcb1, W2Tb, fcb2, out);
}

// Round 5
// 1216.759 us; speedup vs baseline: 3.6481x; 3.6481x over previous
//
#include <hip/hip_runtime.h>

#define NN 50000
#define EE 800000
#define TT 12
#define HH 128
#define LLAYERS 3
#define OO 12

typedef __attribute__((ext_vector_type(8))) short short8;    // 8 bf16 = 4 VGPRs
typedef __attribute__((ext_vector_type(4))) float float4v;   // MFMA acc
typedef unsigned short ushort_t;

#define MFMA_BF16 __builtin_amdgcn_mfma_f32_16x16x32_bf16

__device__ __forceinline__ ushort_t f2b(float f) {   // fp32 -> bf16 RNE
    union { float f; unsigned u; } v; v.f = f;
    unsigned u = v.u;
    return (ushort_t)((u + 0x7FFFu + ((u >> 16) & 1u)) >> 16);
}
__device__ __forceinline__ float b2f(ushort_t b) {
    union { unsigned u; float f; } v; v.u = ((unsigned)b) << 16; return v.f;
}
__device__ __forceinline__ short8 ld8(const ushort_t* p) { return *(const short8*)p; }

__device__ __forceinline__ float sigf(float x) { return 1.f / (1.f + __expf(-x)); }
__device__ __forceinline__ float tanhfast(float x) {
    float a = fabsf(x);
    float t = __expf(-2.f * a);
    float r = (1.f - t) / (1.f + t);
    return copysignf(r, x);
}

// LDS tile helpers: [16][128] bf16 tile (256 B rows), XOR-swizzled (G4).
__device__ __forceinline__ short8 lds_frag(const ushort_t* tile, int row, int kb) {
    int off = (row << 8) + kb;
    off ^= (row & 7) << 4;
    return *(const short8*)((const char*)tile + off);
}
__device__ __forceinline__ void lds_wr16(ushort_t* tile, int row, int cb, ushort_t v) {
    int off = (row << 8) + cb;
    off ^= (row & 7) << 4;
    *(ushort_t*)((char*)tile + off) = v;
}

// ---------------------------------------------------------------------------
// Persistent 2-layer GRU, all 12 timesteps. Column-split across 8 waves:
// wave w owns hidden cols [16w,16w+16) of all gates, both layers -> all
// weight fragments (144 VGPRs) loaded ONCE, resident across the t-loop.
// h0/h1: double-buffered bf16 LDS tiles (no read/write races, 2 barriers/t)
// + single-copy fp32 LDS masters (owner-lane access only).
// Block = 512 thr, 16 nodes. NN % 16 == 0 -> no tail guards in the loop.
// ---------------------------------------------------------------------------
__global__ __launch_bounds__(512, 2)
void gru_all(const float* __restrict__ x,
             const ushort_t* __restrict__ Whh0b, const float* __restrict__ Wih0,
             const float* __restrict__ bih0, const float* __restrict__ bhh0,
             const ushort_t* __restrict__ Wih1b, const ushort_t* __restrict__ Whh1b,
             const float* __restrict__ bih1, const float* __restrict__ bhh1,
             float* __restrict__ h1f, ushort_t* __restrict__ h1b) {
    __shared__ ushort_t h0sA[2048], h0sB[2048], h1sA[2048], h1sB[2048];
    __shared__ float h0m[2048], h1m[2048];
    __shared__ float xsh[192];

    const int tid = threadIdx.x;
    const int wv = tid >> 6, lane = tid & 63;
    const int cl = lane & 15, kg = lane >> 4;
    const int r0 = blockIdx.x * 16;
    const int jj = wv * 16 + cl;          // owned hidden column

    // --- persistent weight fragments (loaded once) ---
    short8 w0[3][4], wxx[3][4], whh[3][4];
#pragma unroll
    for (int g = 0; g < 3; ++g)
#pragma unroll
        for (int ks = 0; ks < 4; ++ks) {
            const size_t ro = (size_t)(g * 128 + jj) * HH + ks * 32 + kg * 8;
            w0[g][ks]  = ld8(Whh0b + ro);
            wxx[g][ks] = ld8(Wih1b + ro);
            whh[g][ks] = ld8(Whh1b + ro);
        }
    const float wiR = Wih0[jj], wiZ = Wih0[jj + 128], wiN = Wih0[jj + 256];
    const float b0R = bih0[jj] + bhh0[jj];
    const float b0Z = bih0[jj + 128] + bhh0[jj + 128];
    const float b0N = bih0[jj + 256];
    const float c0N = bhh0[jj + 256];
    const float b1R = bih1[jj] + bhh1[jj];
    const float b1Z = bih1[jj + 128] + bhh1[jj + 128];
    const float b1N = bih1[jj + 256];
    const float c1N = bhh1[jj + 256];

    if (tid < 192) {
        int row = tid / 12, tt = tid % 12;
        xsh[tid] = x[(size_t)(r0 + row) * TT + tt];
    }
    for (int q = tid; q < 1024; q += 512) {
        ((unsigned*)h0sA)[q] = 0u; ((unsigned*)h0sB)[q] = 0u;
        ((unsigned*)h1sA)[q] = 0u; ((unsigned*)h1sB)[q] = 0u;
    }
    for (int q = tid; q < 2048; q += 512) { h0m[q] = 0.f; h1m[q] = 0.f; }
    __syncthreads();

    ushort_t* h0c = h0sA; ushort_t* h0n = h0sB;
    ushort_t* h1c = h1sA; ushort_t* h1n = h1sB;

#pragma unroll 1
    for (int t = 0; t < TT; ++t) {
        // ---------------- layer 0: read h0c, write h0n ----------------
        short8 a[4];
#pragma unroll
        for (int ks = 0; ks < 4; ++ks)
            a[ks] = lds_frag(h0c, cl, ks * 64 + kg * 16);
        float4v aR = {0,0,0,0}, aZ = {0,0,0,0}, aN = {0,0,0,0};
#pragma unroll
        for (int ks = 0; ks < 4; ++ks) {
            aR = MFMA_BF16(a[ks], w0[0][ks], aR, 0, 0, 0);
            aZ = MFMA_BF16(a[ks], w0[1][ks], aZ, 0, 0, 0);
            aN = MFMA_BF16(a[ks], w0[2][ks], aN, 0, 0, 0);
        }
#pragma unroll
        for (int i = 0; i < 4; ++i) {
            const int rl = kg * 4 + i;
            float xv = xsh[rl * 12 + t];
            float hold = h0m[rl * 128 + jj];
            float r = sigf(fmaf(xv, wiR, b0R) + aR[i]);
            float z = sigf(fmaf(xv, wiZ, b0Z) + aZ[i]);
            float nn2 = tanhfast(fmaf(xv, wiN, b0N) + r * (aN[i] + c0N));
            float hn = (1.f - z) * nn2 + z * hold;
            h0m[rl * 128 + jj] = hn;
            lds_wr16(h0n, rl, jj * 2, f2b(hn));
        }
        __syncthreads();
        // ---------------- layer 1: read h0n,h1c, write h1n ----------------
        short8 an[4], a1[4];
#pragma unroll
        for (int ks = 0; ks < 4; ++ks) {
            an[ks] = lds_frag(h0n, cl, ks * 64 + kg * 16);
            a1[ks] = lds_frag(h1c, cl, ks * 64 + kg * 16);
        }
        float4v xR = {0,0,0,0}, xZ = {0,0,0,0}, xN = {0,0,0,0};
        float4v hR = {0,0,0,0}, hZ = {0,0,0,0}, hN = {0,0,0,0};
#pragma unroll
        for (int ks = 0; ks < 4; ++ks) {
            xR = MFMA_BF16(an[ks], wxx[0][ks], xR, 0, 0, 0);
            xZ = MFMA_BF16(an[ks], wxx[1][ks], xZ, 0, 0, 0);
            xN = MFMA_BF16(an[ks], wxx[2][ks], xN, 0, 0, 0);
            hR = MFMA_BF16(a1[ks], whh[0][ks], hR, 0, 0, 0);
            hZ = MFMA_BF16(a1[ks], whh[1][ks], hZ, 0, 0, 0);
            hN = MFMA_BF16(a1[ks], whh[2][ks], hN, 0, 0, 0);
        }
#pragma unroll
        for (int i = 0; i < 4; ++i) {
            const int rl = kg * 4 + i;
            float hold = h1m[rl * 128 + jj];
            float r = sigf(xR[i] + b1R + hR[i]);
            float z = sigf(xZ[i] + b1Z + hZ[i]);
            float nn2 = tanhfast(xN[i] + b1N + r * (hN[i] + c1N));
            float hn = (1.f - z) * nn2 + z * hold;
            h1m[rl * 128 + jj] = hn;
            lds_wr16(h1n, rl, jj * 2, f2b(hn));
        }
        __syncthreads();
        ushort_t* tmp0 = h0c; h0c = h0n; h0n = tmp0;
        ushort_t* tmp1 = h1c; h1c = h1n; h1n = tmp1;
    }

    // write h1 out (fp32 master + bf16)
#pragma unroll
    for (int i = 0; i < 4; ++i) {
        const int rl = kg * 4 + i;
        const float v = h1m[rl * 128 + jj];
        const size_t off = (size_t)(r0 + rl) * HH + jj;
        h1f[off] = v;
        h1b[off] = f2b(v);
    }
}

// ---------------------------------------------------------------------------
// Dual bf16 GEMM: xl = h1@Wl^T + bl, xr = h1@Wr^T + br (bf16 outputs only).
// ---------------------------------------------------------------------------
__global__ __launch_bounds__(256)
void gemm_dual(const ushort_t* __restrict__ A,
               const ushort_t* __restrict__ B1, const ushort_t* __restrict__ B2,
               const float* __restrict__ bias1, const float* __restrict__ bias2,
               ushort_t* __restrict__ C1, ushort_t* __restrict__ C2) {
    const int wave = threadIdx.x >> 6, lane = threadIdx.x & 63;
    const int r0 = (blockIdx.x * 4 + wave) * 16;
    const int col = lane & 15, kg = lane >> 4;
    const int arow = min(r0 + col, NN - 1);
    short8 a[4];
#pragma unroll
    for (int ks = 0; ks < 4; ++ks)
        a[ks] = ld8(A + (size_t)arow * HH + ks * 32 + kg * 8);
#pragma unroll
    for (int j0 = 0; j0 < 8; ++j0) {
        float4v c1 = {0,0,0,0}, c2 = {0,0,0,0};
        const ushort_t* p1 = B1 + (size_t)(j0 * 16 + col) * HH + kg * 8;
        const ushort_t* p2 = B2 + (size_t)(j0 * 16 + col) * HH + kg * 8;
#pragma unroll
        for (int ks = 0; ks < 4; ++ks) {
            c1 = MFMA_BF16(a[ks], ld8(p1 + ks * 32), c1, 0, 0, 0);
            c2 = MFMA_BF16(a[ks], ld8(p2 + ks * 32), c2, 0, 0, 0);
        }
        const int jj = j0 * 16 + col;
        const float b1 = bias1[jj], b2 = bias2[jj];
#pragma unroll
        for (int i = 0; i < 4; ++i) {
            int node = r0 + kg * 4 + i;
            if (node >= NN) continue;
            C1[(size_t)node * HH + jj] = f2b(c1[i] + b1);
            C2[(size_t)node * HH + jj] = f2b(c2[i] + b2);
        }
    }
}

// ---------------------------------------------------------------------------
// CSR build (by dst).
// ---------------------------------------------------------------------------
__global__ void csr_count(const int* __restrict__ dst, int* __restrict__ cursor) {
    int e = blockIdx.x * 256 + threadIdx.x;
    if (e < EE) atomicAdd(&cursor[dst[e]], 1);
}

__global__ __launch_bounds__(1024)
void csr_scan(int* __restrict__ cursor, int* __restrict__ rowptr) {
    __shared__ int wsum[16];
    __shared__ int carry_s;
    const int tid = threadIdx.x, wv = tid >> 6, ln = tid & 63;
    if (tid == 0) carry_s = 0;
    __syncthreads();
    for (int base = 0; base < NN; base += 1024) {
        int i = base + tid;
        int v = (i < NN) ? cursor[i] : 0;
        int s = v;
#pragma unroll
        for (int d = 1; d < 64; d <<= 1) {
            int t2 = __shfl_up(s, d);
            if (ln >= d) s += t2;
        }
        if (ln == 63) wsum[wv] = s;
        __syncthreads();
        if (wv == 0) {
            int ws2 = (ln < 16) ? wsum[ln] : 0;
#pragma unroll
            for (int d = 1; d < 16; d <<= 1) {
                int t2 = __shfl_up(ws2, d);
                if (ln >= d) ws2 += t2;
            }
            if (ln < 16) wsum[ln] = ws2;
        }
        __syncthreads();
        int wof = wv ? wsum[wv - 1] : 0;
        int excl = carry_s + wof + s - v;
        if (i < NN) { rowptr[i] = excl; cursor[i] = excl; }
        __syncthreads();
        if (tid == 0) carry_s += wsum[15];
    }
    if (threadIdx.x == 0) rowptr[NN] = carry_s;
}

__global__ void csr_fill(const int* __restrict__ dst, int* __restrict__ cursor,
                         int* __restrict__ eidx) {
    int e = blockIdx.x * 256 + threadIdx.x;
    if (e >= EE) return;
    int pos = atomicAdd(&cursor[dst[e]], 1);
    eidx[pos] = e;
}

// ---------------------------------------------------------------------------
// Fused GAT: per dst node (one wave), online-softmax over CSR edges, then
// bias + LayerNorm + ELU + residual. Lane owns channels 2*lane, 2*lane+1
// (same head = lane>>4) -> score reduce is 4 shfl_xor over 16 lanes.
// ---------------------------------------------------------------------------
__global__ __launch_bounds__(256)
void gat_fused(const int* __restrict__ rowptr, const int* __restrict__ eidx,
               const int* __restrict__ src, const float* __restrict__ ea,
               const ushort_t* __restrict__ xlb, const ushort_t* __restrict__ xrb,
               const float* __restrict__ We, const float* __restrict__ att,
               const float* __restrict__ gbias, const float* __restrict__ gamma,
               const float* __restrict__ beta,
               float* __restrict__ h1f, ushort_t* __restrict__ h1b) {
    const int node = (blockIdx.x * 256 + threadIdx.x) >> 6;
    const int lane = threadIdx.x & 63;
    if (node >= NN) return;
    const int c0 = lane * 2;

    unsigned rr = *(const unsigned*)(xrb + (size_t)node * HH + c0);
    const float xrA = b2f((ushort_t)(rr & 0xffffu));
    const float xrB = b2f((ushort_t)(rr >> 16));
    const float2 Wv = *(const float2*)(We + c0);
    const float2 Av = *(const float2*)(att + c0);

    const int beg = rowptr[node], end = rowptr[node + 1];
    float m = -INFINITY, accA = 0.f, accB = 0.f, den = 0.f;

    int i = beg;
    int sN = 0; float ev = 0.f; unsigned rowv = 0;
    if (i < end) {
        int eid = eidx[i]; sN = src[eid]; ev = ea[eid];
        rowv = *(const unsigned*)(xlb + (size_t)sN * HH + c0);
    }
    while (i < end) {
        int sN2 = 0; float ev2 = 0.f; unsigned rowv2 = 0;
        if (i + 1 < end) {
            int eid2 = eidx[i + 1]; sN2 = src[eid2]; ev2 = ea[eid2];
            rowv2 = *(const unsigned*)(xlb + (size_t)sN2 * HH + c0);
        }
        float xlA = b2f((ushort_t)(rowv & 0xffffu));
        float xlB = b2f((ushort_t)(rowv >> 16));
        float mA = xlA + xrA + ev * Wv.x; mA = (mA > 0.f) ? mA : 0.2f * mA;
        float mB = xlB + xrB + ev * Wv.y; mB = (mB > 0.f) ? mB : 0.2f * mB;
        float p = mA * Av.x + mB * Av.y;
        p += __shfl_xor(p, 1); p += __shfl_xor(p, 2);
        p += __shfl_xor(p, 4); p += __shfl_xor(p, 8);
        float mn = fmaxf(m, p);
        float cs = __expf(m - mn);    // 0 on first iteration (m = -inf)
        float w  = __expf(p - mn);
        accA = accA * cs + w * xlA;
        accB = accB * cs + w * xlB;
        den  = den * cs + w;
        m = mn;
        sN = sN2; ev = ev2; rowv = rowv2;
        ++i;
    }
    float invd = 1.f / fmaxf(den, 1e-16f);
    float2 gb = *(const float2*)(gbias + c0);
    float oA = accA * invd + gb.x;
    float oB = accB * invd + gb.y;

    float sum = oA + oB;
    float ssq = oA * oA + oB * oB;
#pragma unroll
    for (int off = 1; off < 64; off <<= 1) {
        sum += __shfl_xor(sum, off);
        ssq += __shfl_xor(ssq, off);
    }
    float mean = sum * (1.f / 128.f);
    float var = ssq * (1.f / 128.f) - mean * mean;
    float inv = rsqrtf(var + 1e-5f);
    float2 gm = *(const float2*)(gamma + c0);
    float2 bt = *(const float2*)(beta + c0);
    float yA = (oA - mean) * inv * gm.x + bt.x;
    float yB = (oB - mean) * inv * gm.y + bt.y;
    yA = (yA > 0.f) ? yA : expm1f(yA);
    yB = (yB > 0.f) ? yB : expm1f(yB);

    float2 hv = *(float2*)(h1f + (size_t)node * HH + c0);
    hv.x += yA; hv.y += yB;
    *(float2*)(h1f + (size_t)node * HH + c0) = hv;
    unsigned pk = (unsigned)f2b(hv.x) | ((unsigned)f2b(hv.y) << 16);
    *(unsigned*)(h1b + (size_t)node * HH + c0) = pk;
}

// ---------------------------------------------------------------------------
// Fused FC head: out = relu(h1@W1^T + b1) @ W2 + b2 via LDS round-trip.
// ---------------------------------------------------------------------------
__global__ __launch_bounds__(256)
void fc_head(const ushort_t* __restrict__ A, const ushort_t* __restrict__ W1b,
             const float* __restrict__ b1, const ushort_t* __restrict__ W2b,
             const float* __restrict__ b2, float* __restrict__ out) {
    __shared__ ushort_t hs[4][2048];
    const int wave = threadIdx.x >> 6, lane = threadIdx.x & 63;
    const int r0 = (blockIdx.x * 4 + wave) * 16;
    const int col = lane & 15, kg = lane >> 4;
    const int arow = min(r0 + col, NN - 1);
    short8 a[4];
#pragma unroll
    for (int ks = 0; ks < 4; ++ks)
        a[ks] = ld8(A + (size_t)arow * HH + ks * 32 + kg * 8);
#pragma unroll
    for (int j0 = 0; j0 < 8; ++j0) {
        float4v acc = {0,0,0,0};
        const ushort_t* bp = W1b + (size_t)(j0 * 16 + col) * HH + kg * 8;
#pragma unroll
        for (int ks = 0; ks < 4; ++ks)
            acc = MFMA_BF16(a[ks], ld8(bp + ks * 32), acc, 0, 0, 0);
        const int jj = j0 * 16 + col;
        const float bj = b1[jj];
#pragma unroll
        for (int i = 0; i < 4; ++i)
            lds_wr16(hs[wave], kg * 4 + i, jj * 2, f2b(fmaxf(acc[i] + bj, 0.f)));
    }
    // second GEMM: [16,128] @ W2b[16 padded cols][128]
    short8 f[4];
#pragma unroll
    for (int ks = 0; ks < 4; ++ks)
        f[ks] = lds_frag(hs[wave], col, ks * 64 + kg * 16);
    float4v acc2 = {0,0,0,0};
#pragma unroll
    for (int ks = 0; ks < 4; ++ks)
        acc2 = MFMA_BF16(f[ks], ld8(W2b + (size_t)col * HH + ks * 32 + kg * 8), acc2, 0, 0, 0);
    if (col < OO) {
        const float bj = b2[col];
#pragma unroll
        for (int i = 0; i < 4; ++i) {
            int node = r0 + kg * 4 + i;
            if (node < NN) out[(size_t)node * OO + col] = acc2[i] + bj;
        }
    }
}

// ---------------------------------------------------------------------------
// Weight conversion kernels
// ---------------------------------------------------------------------------
__global__ void conv_bf16(const float* __restrict__ src, ushort_t* __restrict__ dst, int n) {
    int i = blockIdx.x * 256 + threadIdx.x;
    if (i < n) dst[i] = f2b(src[i]);
}
// fp32 [128,128] -> bf16 transposed: dst[j*128+k] = src[k*128+j]
__global__ void convT_bf16(const float* __restrict__ src, ushort_t* __restrict__ dst) {
    int idx = blockIdx.x * 256 + threadIdx.x;
    if (idx >= 16384) return;
    int r = idx >> 7, c = idx & 127;
    dst[c * 128 + r] = f2b(src[r * 128 + c]);
}
// fcW2 [128,12] -> bf16 [16][128] zero-padded transposed
__global__ void conv_w2(const float* __restrict__ fcW2, ushort_t* __restrict__ W2b) {
    int idx = blockIdx.x * 256 + threadIdx.x;
    if (idx >= 2048) return;
    int j = idx >> 7, k = idx & 127;
    W2b[idx] = (j < OO) ? f2b(fcW2[k * OO + j]) : (ushort_t)0;
}

// ---------------------------------------------------------------------------
extern "C" void kernel_launch(void* const* d_in, const int* in_sizes, int n_in,
                              void* d_out, int out_size, void* d_ws, size_t ws_size,
                              hipStream_t stream) {
    const float* x     = (const float*)d_in[0];
    const int*   ei    = (const int*)d_in[1];
    const int*   src   = ei;
    const int*   dst   = ei + EE;
    const float* ea    = (const float*)d_in[2];
    const float* Wih0  = (const float*)d_in[3];
    const float* Whh0  = (const float*)d_in[4];
    const float* bih0  = (const float*)d_in[5];
    const float* bhh0  = (const float*)d_in[6];
    const float* Wih1  = (const float*)d_in[7];
    const float* Whh1  = (const float*)d_in[8];
    const float* bih1  = (const float*)d_in[9];
    const float* bhh1  = (const float*)d_in[10];
    const float* gWl   = (const float*)d_in[11];
    const float* gbl   = (const float*)d_in[12];
    const float* gWr   = (const float*)d_in[13];
    const float* gbr   = (const float*)d_in[14];
    const float* gWe   = (const float*)d_in[15];
    const float* gatt  = (const float*)d_in[16];
    const float* gbias = (const float*)d_in[17];
    const float* lng   = (const float*)d_in[18];
    const float* lnb   = (const float*)d_in[19];
    const float* fcW1  = (const float*)d_in[20];
    const float* fcb1  = (const float*)d_in[21];
    const float* fcW2  = (const float*)d_in[22];
    const float* fcb2  = (const float*)d_in[23];
    float* out = (float*)d_out;
    float* ws  = (float*)d_ws;

    const size_t NH = (size_t)NN * HH;   // 6.4M elems

    // ushort region
    ushort_t* h1b   = (ushort_t*)ws;          // NH
    ushort_t* xlb   = h1b + NH;               // NH
    ushort_t* xrb   = xlb + NH;               // NH
    ushort_t* Whh0b = xrb + NH;               // 49152
    ushort_t* Wih1b = Whh0b + 49152;
    ushort_t* Whh1b = Wih1b + 49152;
    ushort_t* WlTb  = Whh1b + 49152;          // 3*16384
    ushort_t* WrTb  = WlTb + 49152;           // 3*16384
    ushort_t* W1Tb  = WrTb + 49152;           // 16384
    ushort_t* W2Tb  = W1Tb + 16384;           // 2048
    // total ushorts = 3*NH + 5*49152 + 16384 + 2048 = 19,464,192 (even)

    float* p    = ws + (3 * NH + 5 * 49152 + 16384 + 2048) / 2;
    float* h1f  = p; p += NH;
    int* rowptr = (int*)p;
    int* cursor = rowptr + (NN + 1);
    int* eidx   = cursor + NN;

    // --- weight conversions ---
    conv_bf16<<<192, 256, 0, stream>>>(Whh0, Whh0b, 49152);
    conv_bf16<<<192, 256, 0, stream>>>(Wih1, Wih1b, 49152);
    conv_bf16<<<192, 256, 0, stream>>>(Whh1, Whh1b, 49152);
    for (int l = 0; l < LLAYERS; ++l) {
        convT_bf16<<<64, 256, 0, stream>>>(gWl + (size_t)l * 16384, WlTb + (size_t)l * 16384);
        convT_bf16<<<64, 256, 0, stream>>>(gWr + (size_t)l * 16384, WrTb + (size_t)l * 16384);
    }
    convT_bf16<<<64, 256, 0, stream>>>(fcW1, W1Tb);
    conv_w2<<<8, 256, 0, stream>>>(fcW2, W2Tb);

    // --- CSR by dst (topology shared by all 3 GAT layers) ---
    hipMemsetAsync(cursor, 0, NN * sizeof(int), stream);
    csr_count<<<(EE + 255) / 256, 256, 0, stream>>>(dst, cursor);
    csr_scan<<<1, 1024, 0, stream>>>(cursor, rowptr);
    csr_fill<<<(EE + 255) / 256, 256, 0, stream>>>(dst, cursor, eidx);

    // --- GRU: one persistent kernel, weights register-resident ---
    gru_all<<<NN / 16, 512, 0, stream>>>(x, Whh0b, Wih0, bih0, bhh0,
                                         Wih1b, Whh1b, bih1, bhh1, h1f, h1b);

    // --- GAT layers ---
    const int rowBlocks = (NN + 63) / 64;   // 782
    const int fusedBlocks = (NN + 3) / 4;   // 12500
    for (int l = 0; l < LLAYERS; ++l) {
        gemm_dual<<<rowBlocks, 256, 0, stream>>>(h1b, WlTb + (size_t)l * 16384,
                                                 WrTb + (size_t)l * 16384,
                                                 gbl + l * HH, gbr + l * HH, xlb, xrb);
        gat_fused<<<fusedBlocks, 256, 0, stream>>>(rowptr, eidx, src, ea, xlb, xrb,
                                                   gWe + l * HH, gatt + l * HH,
                                                   gbias + l * HH, lng + l * HH, lnb + l * HH,
                                                   h1f, h1b);
    }

    // --- FC head (fused FC1+FC2) ---
    fc_head<<<rowBlocks, 256, 0, stream>>>(h1b, W1Tb, fcb1, W2Tb, fcb2, out);
}

// Round 6
// 1084.875 us; speedup vs baseline: 4.0916x; 1.1216x over previous
//
#include <hip/hip_runtime.h>

#define NN 50000
#define EE 800000
#define TT 12
#define HH 128
#define LLAYERS 3
#define OO 12

typedef __attribute__((ext_vector_type(8))) short short8;    // 8 bf16 = 4 VGPRs
typedef __attribute__((ext_vector_type(4))) float float4v;   // MFMA acc
typedef unsigned short ushort_t;

#define MFMA_BF16 __builtin_amdgcn_mfma_f32_16x16x32_bf16

__device__ __forceinline__ ushort_t f2b(float f) {   // fp32 -> bf16 RNE
    union { float f; unsigned u; } v; v.f = f;
    unsigned u = v.u;
    return (ushort_t)((u + 0x7FFFu + ((u >> 16) & 1u)) >> 16);
}
__device__ __forceinline__ float b2f(ushort_t b) {
    union { unsigned u; float f; } v; v.u = ((unsigned)b) << 16; return v.f;
}
__device__ __forceinline__ short8 ld8(const ushort_t* p) { return *(const short8*)p; }

__device__ __forceinline__ float rcpf_(float x) { return __builtin_amdgcn_rcpf(x); }
__device__ __forceinline__ float sigf(float x) { return rcpf_(1.f + __expf(-x)); }
__device__ __forceinline__ float tanhfast(float x) {
    float a = fabsf(x);
    float t = __expf(-2.f * a);
    float r = (1.f - t) * rcpf_(1.f + t);
    return copysignf(r, x);
}

// LDS tile helpers: [16][128] bf16 tile (256 B rows), XOR-swizzled (G4).
__device__ __forceinline__ short8 lds_frag(const ushort_t* tile, int row, int kb) {
    int off = (row << 8) + kb;
    off ^= (row & 7) << 4;
    return *(const short8*)((const char*)tile + off);
}
__device__ __forceinline__ void lds_wr16(ushort_t* tile, int row, int cb, ushort_t v) {
    int off = (row << 8) + cb;
    off ^= (row & 7) << 4;
    *(ushort_t*)((char*)tile + off) = v;
}

#define MSTRIDE 132   // fp32 master stride: bank = (4*rl + jj) % 32 -> conflict-free-ish

// ---------------------------------------------------------------------------
// Persistent 2-layer GRU, all 12 timesteps. Column-split across 8 waves:
// wave w owns hidden cols [16w,16w+16) of all gates, both layers -> 144 regs
// of weight fragments loaded ONCE (AGPR-resident), never re-read.
// h0/h1: double-buffered bf16 LDS tiles + padded fp32 LDS masters.
// Block = 512 thr, 16 nodes. NN % 16 == 0 -> no tail guards.
// ---------------------------------------------------------------------------
__global__ __launch_bounds__(512, 2)
void gru_all(const float* __restrict__ x,
             const ushort_t* __restrict__ Whh0b, const float* __restrict__ Wih0,
             const float* __restrict__ bih0, const float* __restrict__ bhh0,
             const ushort_t* __restrict__ Wih1b, const ushort_t* __restrict__ Whh1b,
             const float* __restrict__ bih1, const float* __restrict__ bhh1,
             float* __restrict__ h1f, ushort_t* __restrict__ h1b) {
    __shared__ ushort_t h0sA[2048], h0sB[2048], h1sA[2048], h1sB[2048];
    __shared__ float h0m[16 * MSTRIDE], h1m[16 * MSTRIDE];
    __shared__ float xsh[192];

    const int tid = threadIdx.x;
    const int wv = tid >> 6, lane = tid & 63;
    const int cl = lane & 15, kg = lane >> 4;
    const int r0 = blockIdx.x * 16;
    const int jj = wv * 16 + cl;          // owned hidden column

    // --- persistent weight fragments (loaded once) ---
    short8 w0[3][4], wxx[3][4], whh[3][4];
#pragma unroll
    for (int g = 0; g < 3; ++g)
#pragma unroll
        for (int ks = 0; ks < 4; ++ks) {
            const size_t ro = (size_t)(g * 128 + jj) * HH + ks * 32 + kg * 8;
            w0[g][ks]  = ld8(Whh0b + ro);
            wxx[g][ks] = ld8(Wih1b + ro);
            whh[g][ks] = ld8(Whh1b + ro);
        }
    const float wiR = Wih0[jj], wiZ = Wih0[jj + 128], wiN = Wih0[jj + 256];
    const float b0R = bih0[jj] + bhh0[jj];
    const float b0Z = bih0[jj + 128] + bhh0[jj + 128];
    const float b0N = bih0[jj + 256];
    const float c0N = bhh0[jj + 256];
    const float b1R = bih1[jj] + bhh1[jj];
    const float b1Z = bih1[jj + 128] + bhh1[jj + 128];
    const float b1N = bih1[jj + 256];
    const float c1N = bhh1[jj + 256];

    if (tid < 192) {
        int row = tid / 12, tt = tid % 12;
        xsh[tid] = x[(size_t)(r0 + row) * TT + tt];
    }
    for (int q = tid; q < 1024; q += 512) {
        ((unsigned*)h0sA)[q] = 0u; ((unsigned*)h0sB)[q] = 0u;
        ((unsigned*)h1sA)[q] = 0u; ((unsigned*)h1sB)[q] = 0u;
    }
    for (int q = tid; q < 16 * MSTRIDE; q += 512) { h0m[q] = 0.f; h1m[q] = 0.f; }
    __syncthreads();

    ushort_t* h0c = h0sA; ushort_t* h0n = h0sB;
    ushort_t* h1c = h1sA; ushort_t* h1n = h1sB;

#pragma unroll 1
    for (int t = 0; t < TT; ++t) {
        // ---------------- layer 0: read h0c, write h0n ----------------
        {
            short8 a[4];
#pragma unroll
            for (int ks = 0; ks < 4; ++ks)
                a[ks] = lds_frag(h0c, cl, ks * 64 + kg * 16);
            float4v aR = {0,0,0,0}, aZ = {0,0,0,0}, aN = {0,0,0,0};
#pragma unroll
            for (int ks = 0; ks < 4; ++ks) {
                aR = MFMA_BF16(a[ks], w0[0][ks], aR, 0, 0, 0);
                aZ = MFMA_BF16(a[ks], w0[1][ks], aZ, 0, 0, 0);
                aN = MFMA_BF16(a[ks], w0[2][ks], aN, 0, 0, 0);
            }
#pragma unroll
            for (int i = 0; i < 4; ++i) {
                const int rl = kg * 4 + i;
                float xv = xsh[rl * 12 + t];
                float hold = h0m[rl * MSTRIDE + jj];
                float r = sigf(fmaf(xv, wiR, b0R) + aR[i]);
                float z = sigf(fmaf(xv, wiZ, b0Z) + aZ[i]);
                float nn2 = tanhfast(fmaf(xv, wiN, b0N) + r * (aN[i] + c0N));
                float hn = fmaf(z, hold - nn2, nn2);
                h0m[rl * MSTRIDE + jj] = hn;
                lds_wr16(h0n, rl, jj * 2, f2b(hn));
            }
        }
        __syncthreads();
        // ---------------- layer 1: read h0n,h1c, write h1n ----------------
        {
            short8 an[4], a1[4];
#pragma unroll
            for (int ks = 0; ks < 4; ++ks) {
                an[ks] = lds_frag(h0n, cl, ks * 64 + kg * 16);
                a1[ks] = lds_frag(h1c, cl, ks * 64 + kg * 16);
            }
            float4v xR = {0,0,0,0}, xZ = {0,0,0,0}, xN = {0,0,0,0};
            float4v hR = {0,0,0,0}, hZ = {0,0,0,0}, hN = {0,0,0,0};
#pragma unroll
            for (int ks = 0; ks < 4; ++ks) {
                xR = MFMA_BF16(an[ks], wxx[0][ks], xR, 0, 0, 0);
                xZ = MFMA_BF16(an[ks], wxx[1][ks], xZ, 0, 0, 0);
                xN = MFMA_BF16(an[ks], wxx[2][ks], xN, 0, 0, 0);
                hR = MFMA_BF16(a1[ks], whh[0][ks], hR, 0, 0, 0);
                hZ = MFMA_BF16(a1[ks], whh[1][ks], hZ, 0, 0, 0);
                hN = MFMA_BF16(a1[ks], whh[2][ks], hN, 0, 0, 0);
            }
#pragma unroll
            for (int i = 0; i < 4; ++i) {
                const int rl = kg * 4 + i;
                float hold = h1m[rl * MSTRIDE + jj];
                float r = sigf(xR[i] + b1R + hR[i]);
                float z = sigf(xZ[i] + b1Z + hZ[i]);
                float nn2 = tanhfast(xN[i] + b1N + r * (hN[i] + c1N));
                float hn = fmaf(z, hold - nn2, nn2);
                h1m[rl * MSTRIDE + jj] = hn;
                lds_wr16(h1n, rl, jj * 2, f2b(hn));
            }
        }
        __syncthreads();
        ushort_t* tmp0 = h0c; h0c = h0n; h0n = tmp0;
        ushort_t* tmp1 = h1c; h1c = h1n; h1n = tmp1;
    }

    // write h1 out (fp32 master + bf16)
#pragma unroll
    for (int i = 0; i < 4; ++i) {
        const int rl = kg * 4 + i;
        const float v = h1m[rl * MSTRIDE + jj];
        const size_t off = (size_t)(r0 + rl) * HH + jj;
        h1f[off] = v;
        h1b[off] = f2b(v);
    }
}

// ---------------------------------------------------------------------------
// Dual bf16 GEMM: xl = h1@Wl^T + bl, xr = h1@Wr^T + br (bf16 outputs only).
// ---------------------------------------------------------------------------
__global__ __launch_bounds__(256)
void gemm_dual(const ushort_t* __restrict__ A,
               const ushort_t* __restrict__ B1, const ushort_t* __restrict__ B2,
               const float* __restrict__ bias1, const float* __restrict__ bias2,
               ushort_t* __restrict__ C1, ushort_t* __restrict__ C2) {
    const int wave = threadIdx.x >> 6, lane = threadIdx.x & 63;
    const int r0 = (blockIdx.x * 4 + wave) * 16;
    const int col = lane & 15, kg = lane >> 4;
    const int arow = min(r0 + col, NN - 1);
    short8 a[4];
#pragma unroll
    for (int ks = 0; ks < 4; ++ks)
        a[ks] = ld8(A + (size_t)arow * HH + ks * 32 + kg * 8);
#pragma unroll
    for (int j0 = 0; j0 < 8; ++j0) {
        float4v c1 = {0,0,0,0}, c2 = {0,0,0,0};
        const ushort_t* p1 = B1 + (size_t)(j0 * 16 + col) * HH + kg * 8;
        const ushort_t* p2 = B2 + (size_t)(j0 * 16 + col) * HH + kg * 8;
#pragma unroll
        for (int ks = 0; ks < 4; ++ks) {
            c1 = MFMA_BF16(a[ks], ld8(p1 + ks * 32), c1, 0, 0, 0);
            c2 = MFMA_BF16(a[ks], ld8(p2 + ks * 32), c2, 0, 0, 0);
        }
        const int jj = j0 * 16 + col;
        const float b1 = bias1[jj], b2 = bias2[jj];
#pragma unroll
        for (int i = 0; i < 4; ++i) {
            int node = r0 + kg * 4 + i;
            if (node >= NN) continue;
            C1[(size_t)node * HH + jj] = f2b(c1[i] + b1);
            C2[(size_t)node * HH + jj] = f2b(c2[i] + b2);
        }
    }
}

// ---------------------------------------------------------------------------
// CSR build (by dst).
// ---------------------------------------------------------------------------
__global__ void csr_count(const int* __restrict__ dst, int* __restrict__ cursor) {
    int e = blockIdx.x * 256 + threadIdx.x;
    if (e < EE) atomicAdd(&cursor[dst[e]], 1);
}

__global__ __launch_bounds__(1024)
void csr_scan(int* __restrict__ cursor, int* __restrict__ rowptr) {
    __shared__ int wsum[16];
    __shared__ int carry_s;
    const int tid = threadIdx.x, wv = tid >> 6, ln = tid & 63;
    if (tid == 0) carry_s = 0;
    __syncthreads();
    for (int base = 0; base < NN; base += 1024) {
        int i = base + tid;
        int v = (i < NN) ? cursor[i] : 0;
        int s = v;
#pragma unroll
        for (int d = 1; d < 64; d <<= 1) {
            int t2 = __shfl_up(s, d);
            if (ln >= d) s += t2;
        }
        if (ln == 63) wsum[wv] = s;
        __syncthreads();
        if (wv == 0) {
            int ws2 = (ln < 16) ? wsum[ln] : 0;
#pragma unroll
            for (int d = 1; d < 16; d <<= 1) {
                int t2 = __shfl_up(ws2, d);
                if (ln >= d) ws2 += t2;
            }
            if (ln < 16) wsum[ln] = ws2;
        }
        __syncthreads();
        int wof = wv ? wsum[wv - 1] : 0;
        int excl = carry_s + wof + s - v;
        if (i < NN) { rowptr[i] = excl; cursor[i] = excl; }
        __syncthreads();
        if (tid == 0) carry_s += wsum[15];
    }
    if (threadIdx.x == 0) rowptr[NN] = carry_s;
}

__global__ void csr_fill(const int* __restrict__ dst, int* __restrict__ cursor,
                         int* __restrict__ eidx) {
    int e = blockIdx.x * 256 + threadIdx.x;
    if (e >= EE) return;
    int pos = atomicAdd(&cursor[dst[e]], 1);
    eidx[pos] = e;
}

// ---------------------------------------------------------------------------
// Fused GAT: per dst node (one wave), online-softmax over CSR edges, then
// bias + LayerNorm + ELU + residual. Lane owns channels 2*lane, 2*lane+1
// (same head = lane>>4) -> score reduce is 4 shfl_xor over 16 lanes.
// ---------------------------------------------------------------------------
__global__ __launch_bounds__(256)
void gat_fused(const int* __restrict__ rowptr, const int* __restrict__ eidx,
               const int* __restrict__ src, const float* __restrict__ ea,
               const ushort_t* __restrict__ xlb, const ushort_t* __restrict__ xrb,
               const float* __restrict__ We, const float* __restrict__ att,
               const float* __restrict__ gbias, const float* __restrict__ gamma,
               const float* __restrict__ beta,
               float* __restrict__ h1f, ushort_t* __restrict__ h1b) {
    const int node = (blockIdx.x * 256 + threadIdx.x) >> 6;
    const int lane = threadIdx.x & 63;
    if (node >= NN) return;
    const int c0 = lane * 2;

    unsigned rr = *(const unsigned*)(xrb + (size_t)node * HH + c0);
    const float xrA = b2f((ushort_t)(rr & 0xffffu));
    const float xrB = b2f((ushort_t)(rr >> 16));
    const float2 Wv = *(const float2*)(We + c0);
    const float2 Av = *(const float2*)(att + c0);

    const int beg = rowptr[node], end = rowptr[node + 1];
    float m = -INFINITY, accA = 0.f, accB = 0.f, den = 0.f;

    int i = beg;
    float ev = 0.f; unsigned rowv = 0;
    if (i < end) {
        int eid = eidx[i]; int sN = src[eid]; ev = ea[eid];
        rowv = *(const unsigned*)(xlb + (size_t)sN * HH + c0);
    }
    while (i < end) {
        float ev2 = 0.f; unsigned rowv2 = 0;
        if (i + 1 < end) {
            int eid2 = eidx[i + 1]; int sN2 = src[eid2]; ev2 = ea[eid2];
            rowv2 = *(const unsigned*)(xlb + (size_t)sN2 * HH + c0);
        }
        float xlA = b2f((ushort_t)(rowv & 0xffffu));
        float xlB = b2f((ushort_t)(rowv >> 16));
        float mA = xlA + xrA + ev * Wv.x; mA = (mA > 0.f) ? mA : 0.2f * mA;
        float mB = xlB + xrB + ev * Wv.y; mB = (mB > 0.f) ? mB : 0.2f * mB;
        float p = mA * Av.x + mB * Av.y;
        p += __shfl_xor(p, 1); p += __shfl_xor(p, 2);
        p += __shfl_xor(p, 4); p += __shfl_xor(p, 8);
        float mn = fmaxf(m, p);
        float cs = __expf(m - mn);    // 0 on first iteration (m = -inf)
        float w  = __expf(p - mn);
        accA = accA * cs + w * xlA;
        accB = accB * cs + w * xlB;
        den  = den * cs + w;
        m = mn;
        ev = ev2; rowv = rowv2;
        ++i;
    }
    float invd = 1.f / fmaxf(den, 1e-16f);
    float2 gb = *(const float2*)(gbias + c0);
    float oA = accA * invd + gb.x;
    float oB = accB * invd + gb.y;

    float sum = oA + oB;
    float ssq = oA * oA + oB * oB;
#pragma unroll
    for (int off = 1; off < 64; off <<= 1) {
        sum += __shfl_xor(sum, off);
        ssq += __shfl_xor(ssq, off);
    }
    float mean = sum * (1.f / 128.f);
    float var = ssq * (1.f / 128.f) - mean * mean;
    float inv = rsqrtf(var + 1e-5f);
    float2 gm = *(const float2*)(gamma + c0);
    float2 bt = *(const float2*)(beta + c0);
    float yA = (oA - mean) * inv * gm.x + bt.x;
    float yB = (oB - mean) * inv * gm.y + bt.y;
    yA = (yA > 0.f) ? yA : expm1f(yA);
    yB = (yB > 0.f) ? yB : expm1f(yB);

    float2 hv = *(float2*)(h1f + (size_t)node * HH + c0);
    hv.x += yA; hv.y += yB;
    *(float2*)(h1f + (size_t)node * HH + c0) = hv;
    unsigned pk = (unsigned)f2b(hv.x) | ((unsigned)f2b(hv.y) << 16);
    *(unsigned*)(h1b + (size_t)node * HH + c0) = pk;
}

// ---------------------------------------------------------------------------
// Fused FC head: out = relu(h1@W1^T + b1) @ W2 + b2 via LDS round-trip.
// ---------------------------------------------------------------------------
__global__ __launch_bounds__(256)
void fc_head(const ushort_t* __restrict__ A, const ushort_t* __restrict__ W1b,
             const float* __restrict__ b1, const ushort_t* __restrict__ W2b,
             const float* __restrict__ b2, float* __restrict__ out) {
    __shared__ ushort_t hs[4][2048];
    const int wave = threadIdx.x >> 6, lane = threadIdx.x & 63;
    const int r0 = (blockIdx.x * 4 + wave) * 16;
    const int col = lane & 15, kg = lane >> 4;
    const int arow = min(r0 + col, NN - 1);
    short8 a[4];
#pragma unroll
    for (int ks = 0; ks < 4; ++ks)
        a[ks] = ld8(A + (size_t)arow * HH + ks * 32 + kg * 8);
#pragma unroll
    for (int j0 = 0; j0 < 8; ++j0) {
        float4v acc = {0,0,0,0};
        const ushort_t* bp = W1b + (size_t)(j0 * 16 + col) * HH + kg * 8;
#pragma unroll
        for (int ks = 0; ks < 4; ++ks)
            acc = MFMA_BF16(a[ks], ld8(bp + ks * 32), acc, 0, 0, 0);
        const int jj = j0 * 16 + col;
        const float bj = b1[jj];
#pragma unroll
        for (int i = 0; i < 4; ++i)
            lds_wr16(hs[wave], kg * 4 + i, jj * 2, f2b(fmaxf(acc[i] + bj, 0.f)));
    }
    // second GEMM: [16,128] @ W2b[16 padded cols][128]
    short8 f[4];
#pragma unroll
    for (int ks = 0; ks < 4; ++ks)
        f[ks] = lds_frag(hs[wave], col, ks * 64 + kg * 16);
    float4v acc2 = {0,0,0,0};
#pragma unroll
    for (int ks = 0; ks < 4; ++ks)
        acc2 = MFMA_BF16(f[ks], ld8(W2b + (size_t)col * HH + ks * 32 + kg * 8), acc2, 0, 0, 0);
    if (col < OO) {
        const float bj = b2[col];
#pragma unroll
        for (int i = 0; i < 4; ++i) {
            int node = r0 + kg * 4 + i;
            if (node < NN) out[(size_t)node * OO + col] = acc2[i] + bj;
        }
    }
}

// ---------------------------------------------------------------------------
// ONE merged weight-conversion kernel.
// [0,147456): straight bf16 conv of Whh0|Wih1|Whh1 (49152 each)
// [147456,262144): 7 transposed 128x128 convs: Wl0..2, Wr0..2, fcW1
// [262144,264192): fcW2 [128,12] -> bf16 [16][128] zero-padded transposed
// ---------------------------------------------------------------------------
__global__ void conv_all(const float* __restrict__ Whh0, const float* __restrict__ Wih1,
                         const float* __restrict__ Whh1, const float* __restrict__ gWl,
                         const float* __restrict__ gWr, const float* __restrict__ fcW1,
                         const float* __restrict__ fcW2,
                         ushort_t* __restrict__ Whh0b, ushort_t* __restrict__ Wih1b,
                         ushort_t* __restrict__ Whh1b, ushort_t* __restrict__ WlTb,
                         ushort_t* __restrict__ WrTb, ushort_t* __restrict__ W1Tb,
                         ushort_t* __restrict__ W2Tb) {
    int idx = blockIdx.x * 256 + threadIdx.x;
    if (idx < 147456) {
        const float* s; ushort_t* d; int o = idx;
        if (o < 49152)        { s = Whh0; d = Whh0b; }
        else if (o < 98304)   { s = Wih1; d = Wih1b; o -= 49152; }
        else                  { s = Whh1; d = Whh1b; o -= 98304; }
        d[o] = f2b(s[o]);
    } else if (idx < 262144) {
        int local = idx - 147456;
        int mt = local >> 14, o = local & 16383;
        int r = o >> 7, c = o & 127;
        const float* s; ushort_t* d;
        if (mt < 3)      { s = gWl + (size_t)mt * 16384;       d = WlTb + (size_t)mt * 16384; }
        else if (mt < 6) { s = gWr + (size_t)(mt - 3) * 16384; d = WrTb + (size_t)(mt - 3) * 16384; }
        else             { s = fcW1;                            d = W1Tb; }
        d[c * 128 + r] = f2b(s[r * 128 + c]);
    } else if (idx < 264192) {
        int o = idx - 262144;
        int j = o >> 7, k = o & 127;
        W2Tb[o] = (j < OO) ? f2b(fcW2[k * OO + j]) : (ushort_t)0;
    }
}

// ---------------------------------------------------------------------------
extern "C" void kernel_launch(void* const* d_in, const int* in_sizes, int n_in,
                              void* d_out, int out_size, void* d_ws, size_t ws_size,
                              hipStream_t stream) {
    const float* x     = (const float*)d_in[0];
    const int*   ei    = (const int*)d_in[1];
    const int*   src   = ei;
    const int*   dst   = ei + EE;
    const float* ea    = (const float*)d_in[2];
    const float* Wih0  = (const float*)d_in[3];
    const float* Whh0  = (const float*)d_in[4];
    const float* bih0  = (const float*)d_in[5];
    const float* bhh0  = (const float*)d_in[6];
    const float* Wih1  = (const float*)d_in[7];
    const float* Whh1  = (const float*)d_in[8];
    const float* bih1  = (const float*)d_in[9];
    const float* bhh1  = (const float*)d_in[10];
    const float* gWl   = (const float*)d_in[11];
    const float* gbl   = (const float*)d_in[12];
    const float* gWr   = (const float*)d_in[13];
    const float* gbr   = (const float*)d_in[14];
    const float* gWe   = (const float*)d_in[15];
    const float* gatt  = (const float*)d_in[16];
    const float* gbias = (const float*)d_in[17];
    const float* lng   = (const float*)d_in[18];
    const float* lnb   = (const float*)d_in[19];
    const float* fcW1  = (const float*)d_in[20];
    const float* fcb1  = (const float*)d_in[21];
    const float* fcW2  = (const float*)d_in[22];
    const float* fcb2  = (const float*)d_in[23];
    float* out = (float*)d_out;
    float* ws  = (float*)d_ws;

    const size_t NH = (size_t)NN * HH;   // 6.4M elems

    // ushort region
    ushort_t* h1b   = (ushort_t*)ws;          // NH
    ushort_t* xlb   = h1b + NH;               // NH
    ushort_t* xrb   = xlb + NH;               // NH
    ushort_t* Whh0b = xrb + NH;               // 49152
    ushort_t* Wih1b = Whh0b + 49152;
    ushort_t* Whh1b = Wih1b + 49152;
    ushort_t* WlTb  = Whh1b + 49152;          // 3*16384
    ushort_t* WrTb  = WlTb + 49152;           // 3*16384
    ushort_t* W1Tb  = WrTb + 49152;           // 16384
    ushort_t* W2Tb  = W1Tb + 16384;           // 2048
    // total ushorts = 3*NH + 5*49152 + 16384 + 2048 = 19,464,192 (even)

    float* p    = ws + (3 * NH + 5 * 49152 + 16384 + 2048) / 2;
    float* h1f  = p; p += NH;
    int* rowptr = (int*)p;
    int* cursor = rowptr + (NN + 1);
    int* eidx   = cursor + NN;

    // --- weight conversions (single launch) ---
    conv_all<<<1032, 256, 0, stream>>>(Whh0, Wih1, Whh1, gWl, gWr, fcW1, fcW2,
                                       Whh0b, Wih1b, Whh1b, WlTb, WrTb, W1Tb, W2Tb);

    // --- CSR by dst (topology shared by all 3 GAT layers) ---
    hipMemsetAsync(cursor, 0, NN * sizeof(int), stream);
    csr_count<<<(EE + 255) / 256, 256, 0, stream>>>(dst, cursor);
    csr_scan<<<1, 1024, 0, stream>>>(cursor, rowptr);
    csr_fill<<<(EE + 255) / 256, 256, 0, stream>>>(dst, cursor, eidx);

    // --- GRU: one persistent kernel, weights register-resident ---
    gru_all<<<NN / 16, 512, 0, stream>>>(x, Whh0b, Wih0, bih0, bhh0,
                                         Wih1b, Whh1b, bih1, bhh1, h1f, h1b);

    // --- GAT layers ---
    const int rowBlocks = (NN + 63) / 64;   // 782
    const int fusedBlocks = (NN + 3) / 4;   // 12500
    for (int l = 0; l < LLAYERS; ++l) {
        gemm_dual<<<rowBlocks, 256, 0, stream>>>(h1b, WlTb + (size_t)l * 16384,
                                                 WrTb + (size_t)l * 16384,
                                                 gbl + l * HH, gbr + l * HH, xlb, xrb);
        gat_fused<<<fusedBlocks, 256, 0, stream>>>(rowptr, eidx, src, ea, xlb, xrb,
                                                   gWe + l * HH, gatt + l * HH,
                                                   gbias + l * HH, lng + l * HH, lnb + l * HH,
                                                   h1f, h1b);
    }

    // --- FC head (fused FC1+FC2) ---
    fc_head<<<rowBlocks, 256, 0, stream>>>(h1b, W1Tb, fcb1, W2Tb, fcb2, out);
}